// Round 6
// baseline (394.957 us; speedup 1.0000x reference)
//
#include <hip/hip_runtime.h>

#define ALPHA 0.01f
#define BIN_SHIFT 8
#define BIN_SIZE 256          // buckets per bin

typedef __attribute__((ext_vector_type(8))) short short8v;   // 8 x bf16 bits (4 VGPR)
typedef __attribute__((ext_vector_type(4))) float float4v;   // MFMA acc

// split fp32 -> bf16 hi + bf16 lo (truncation; residual capture => ~2^-24 total rel err)
__device__ __forceinline__ void bsplit(float x, unsigned short& hi, unsigned short& lo) {
  unsigned u = __float_as_uint(x);
  hi = (unsigned short)(u >> 16);
  float r = x - __uint_as_float(u & 0xFFFF0000u);
  lo = (unsigned short)(__float_as_uint(r) >> 16);
}

__device__ __forceinline__ void frag_from8(const float* v, short8v& hi, short8v& lo) {
#pragma unroll
  for (int e = 0; e < 8; ++e) {
    unsigned short h, l;
    bsplit(v[e], h, l);
    hi[e] = (short)h;
    lo[e] = (short)l;
  }
}

// ---------------- fused MFMA: G[N,16] = relu(X[N,128] @ W^T + b) @ Wo^T ---------------
__global__ __launch_bounds__(256, 2) void fused_mfma_kernel(
    const float* __restrict__ X, const float* __restrict__ W,
    const float* __restrict__ B, const float* __restrict__ Wo,
    float* __restrict__ G, int N)
{
  __shared__ char smem[65536 + 10368] __attribute__((aligned(16)));
  unsigned short* Whi = (unsigned short*)smem;
  unsigned short* Wlo = (unsigned short*)(smem + 32768);
  unsigned short* WoHi = (unsigned short*)(smem + 65536);
  unsigned short* WoLo = (unsigned short*)(smem + 65536 + 4096);

  const int t = threadIdx.x;
  const int wave = t >> 6;
  const int lane = t & 63;
  const int s = lane & 15;
  const int q = lane >> 4;
  float* hbuf = (float*)(smem + 65536 + wave * 2176);  // [32][17] f32, per-wave

#pragma unroll
  for (int i = 0; i < 32; ++i) {
    int p = i * 256 + t;
    int row = p >> 6, c2 = p & 63;
    float w0 = W[row * 128 + c2 * 2];
    float w1 = W[row * 128 + c2 * 2 + 1];
    unsigned short h0, l0, h1, l1;
    bsplit(w0, h0, l0); bsplit(w1, h1, l1);
    int u32idx = row * 64 + ((((c2 * 4) ^ ((row & 7) << 4))) >> 2);
    ((unsigned*)Whi)[u32idx] = (unsigned)h0 | ((unsigned)h1 << 16);
    ((unsigned*)Wlo)[u32idx] = (unsigned)l0 | ((unsigned)l1 << 16);
  }
#pragma unroll
  for (int i = 0; i < 4; ++i) {
    int p = i * 256 + t;
    int row = p >> 6, c2 = p & 63;
    float w0 = Wo[row * 128 + c2 * 2];
    float w1 = Wo[row * 128 + c2 * 2 + 1];
    unsigned short h0, l0, h1, l1;
    bsplit(w0, h0, l0); bsplit(w1, h1, l1);
    int u32idx = row * 64 + ((((c2 * 4) ^ ((row & 7) << 4))) >> 2);
    ((unsigned*)WoHi)[u32idx] = (unsigned)h0 | ((unsigned)h1 << 16);
    ((unsigned*)WoLo)[u32idx] = (unsigned)l0 | ((unsigned)l1 << 16);
  }
  __syncthreads();

  short8v woh[4], wol[4];
  const int woswz = (s & 7) << 4;
#pragma unroll
  for (int ks = 0; ks < 4; ++ks) {
    int off = s * 256 + ((ks * 64 + q * 16) ^ woswz);
    woh[ks] = *(const short8v*)((char*)WoHi + off);
    wol[ks] = *(const short8v*)((char*)WoLo + off);
  }
  float bv[8];
#pragma unroll
  for (int nt = 0; nt < 8; ++nt) bv[nt] = B[nt * 16 + s];
  __syncthreads();  // Wo staging area now reusable as hbuf

  const int nchunks = (N + 127) >> 7;
  const int bswz = (s & 7) << 4;

  for (int chunk = blockIdx.x; chunk < nchunks; chunk += gridDim.x) {
    const int rowbase = chunk * 128 + wave * 32;

    short8v ahi[2][4], alo[2][4];
#pragma unroll
    for (int mt = 0; mt < 2; ++mt) {
      int row = rowbase + mt * 16 + s;
      int crow = row < N ? row : (N - 1);
      const float* xr = X + (size_t)crow * 128;
#pragma unroll
      for (int ks = 0; ks < 4; ++ks) {
        float4 f0 = *(const float4*)(xr + ks * 32 + q * 8);
        float4 f1 = *(const float4*)(xr + ks * 32 + q * 8 + 4);
        float v[8] = {f0.x, f0.y, f0.z, f0.w, f1.x, f1.y, f1.z, f1.w};
        frag_from8(v, ahi[mt][ks], alo[mt][ks]);
      }
    }

    float4v acc[2][8];
#pragma unroll
    for (int mt = 0; mt < 2; ++mt)
#pragma unroll
      for (int nt = 0; nt < 8; ++nt) acc[mt][nt] = (float4v){0.f, 0.f, 0.f, 0.f};

#pragma unroll
    for (int ks = 0; ks < 4; ++ks) {
      short8v bh[8];
#pragma unroll
      for (int nt = 0; nt < 8; ++nt) {
        int c = nt * 16 + s;
        int off = c * 256 + ((ks * 64 + q * 16) ^ bswz);
        bh[nt] = *(const short8v*)((char*)Whi + off);
      }
#pragma unroll
      for (int nt = 0; nt < 8; ++nt) {
#pragma unroll
        for (int mt = 0; mt < 2; ++mt) {
          acc[mt][nt] = __builtin_amdgcn_mfma_f32_16x16x32_bf16(ahi[mt][ks], bh[nt], acc[mt][nt], 0, 0, 0);
          acc[mt][nt] = __builtin_amdgcn_mfma_f32_16x16x32_bf16(alo[mt][ks], bh[nt], acc[mt][nt], 0, 0, 0);
        }
      }
#pragma unroll
      for (int nt = 0; nt < 8; ++nt) {
        int c = nt * 16 + s;
        int off = c * 256 + ((ks * 64 + q * 16) ^ bswz);
        short8v bl = *(const short8v*)((char*)Wlo + off);
#pragma unroll
        for (int mt = 0; mt < 2; ++mt)
          acc[mt][nt] = __builtin_amdgcn_mfma_f32_16x16x32_bf16(ahi[mt][ks], bl, acc[mt][nt], 0, 0, 0);
      }
    }

#pragma unroll
    for (int mt = 0; mt < 2; ++mt) {
      float4v gacc = (float4v){0.f, 0.f, 0.f, 0.f};
#pragma unroll
      for (int ks = 0; ks < 4; ++ks) {
#pragma unroll
        for (int j = 0; j < 2; ++j) {
          int nt = 2 * ks + j;
          int cl = j * 16 + s;
#pragma unroll
          for (int e = 0; e < 4; ++e)
            hbuf[cl * 17 + q * 4 + e] = fmaxf(acc[mt][nt][e] + bv[nt], 0.f);
        }
        float hv[8];
#pragma unroll
        for (int e = 0; e < 8; ++e) hv[e] = hbuf[(q * 8 + e) * 17 + s];
        short8v hh, hl;
        frag_from8(hv, hh, hl);
        gacc = __builtin_amdgcn_mfma_f32_16x16x32_bf16(hh, woh[ks], gacc, 0, 0, 0);
        gacc = __builtin_amdgcn_mfma_f32_16x16x32_bf16(hl, woh[ks], gacc, 0, 0, 0);
        gacc = __builtin_amdgcn_mfma_f32_16x16x32_bf16(hh, wol[ks], gacc, 0, 0, 0);
      }
      int grow = rowbase + mt * 16 + 4 * q;
#pragma unroll
      for (int e = 0; e < 4; ++e)
        if (grow + e < N) G[(size_t)(grow + e) * 16 + s] = gacc[e];
    }
  }
}

// ---------------- coarse bin histogram over two edge lists ---------------------------
// bucket = dst*mul + add (per list); bin = bucket >> BIN_SHIFT. nbins <= 1024.
__global__ __launch_bounds__(256) void bin_hist_kernel(
    const int* __restrict__ dA, int EA, const int* __restrict__ dB, int EB,
    int mulA, int addA, int mulB, int addB, int nbins, int* __restrict__ binHist)
{
  __shared__ int h[1024];
  for (int k = threadIdx.x; k < nbins; k += 256) h[k] = 0;
  __syncthreads();
  const int E = EA + EB;
  for (int i = blockIdx.x * 256 + threadIdx.x; i < E; i += gridDim.x * 256) {
    int bucket = (i < EA) ? dA[i] * mulA + addA : dB[i - EA] * mulB + addB;
    atomicAdd(&h[bucket >> BIN_SHIFT], 1);
  }
  __syncthreads();
  for (int k = threadIdx.x; k < nbins; k += 256)
    if (h[k]) atomicAdd(&binHist[k], h[k]);
}

// ---------------- exclusive scan over <=1024 bins (single block) ---------------------
__global__ __launch_bounds__(1024) void bin_scan_kernel(
    const int* __restrict__ hist, int* __restrict__ start, int* __restrict__ cursor, int n)
{
  __shared__ int tmp[1024];
  int t = threadIdx.x;
  int v = (t < n) ? hist[t] : 0;
  tmp[t] = v;
  __syncthreads();
  for (int d = 1; d < 1024; d <<= 1) {
    int add = (t >= d) ? tmp[t - d] : 0;
    __syncthreads();
    tmp[t] += add;
    __syncthreads();
  }
  int excl = tmp[t] - v;
  if (t < n) { start[t] = excl; cursor[t] = excl; }
  if (t == n - 1) start[n] = tmp[t];
}

// ---------------- binned fill: write packed codes bin-contiguously -------------------
// code = (src << BIN_SHIFT) | (bucket & (BIN_SIZE-1)). Per 4096-edge block: LDS hist,
// one global atomic per (block,bin) to reserve, then clustered writes -> L2 aggregates.
__global__ __launch_bounds__(256) void bin_fill_kernel(
    const int* __restrict__ sA, const int* __restrict__ dA, int EA,
    const int* __restrict__ sB, const int* __restrict__ dB, int EB,
    int mulA, int addA, int mulB, int addB, int nbins,
    int* __restrict__ binCursor, unsigned* __restrict__ binned)
{
  __shared__ int h[1024];
  __shared__ int base[1024];
  const int E = EA + EB;
  const int c0 = blockIdx.x * 4096;
  const int c1 = (c0 + 4096 < E) ? c0 + 4096 : E;
  for (int k = threadIdx.x; k < nbins; k += 256) h[k] = 0;
  __syncthreads();
  for (int i = c0 + threadIdx.x; i < c1; i += 256) {
    int bucket = (i < EA) ? dA[i] * mulA + addA : dB[i - EA] * mulB + addB;
    atomicAdd(&h[bucket >> BIN_SHIFT], 1);
  }
  __syncthreads();
  for (int k = threadIdx.x; k < nbins; k += 256) {
    int c = h[k];
    base[k] = c ? atomicAdd(&binCursor[k], c) : 0;
    h[k] = 0;
  }
  __syncthreads();
  for (int i = c0 + threadIdx.x; i < c1; i += 256) {
    int s, bucket;
    if (i < EA) { s = sA[i]; bucket = dA[i] * mulA + addA; }
    else { int j = i - EA; s = sB[j]; bucket = dB[j] * mulB + addB; }
    int bin = bucket >> BIN_SHIFT;
    int r = atomicAdd(&h[bin], 1);
    binned[base[bin] + r] = ((unsigned)s << BIN_SHIFT) | (unsigned)(bucket & (BIN_SIZE - 1));
  }
}

// ---------------- stage A accumulate: pay = ALPHA*g_self + 0.5*mean(g_m) -------------
// One block per bin (256 buckets). LDS f32 accumulators; 16 lanes per edge read a
// coalesced 64B source vector; coalesced writeout. Buckets [0,NU)=users, [NU,NU+ND)=dirs.
__global__ __launch_bounds__(256) void accum_pay_kernel(
    const unsigned* __restrict__ binned, const int* __restrict__ binStart,
    const float* __restrict__ g_m, const float* __restrict__ g_u,
    const float* __restrict__ g_d, int NU, int ND,
    float* __restrict__ pay_u, float* __restrict__ pay_d)
{
  __shared__ float acc[BIN_SIZE * 16];
  __shared__ int cnt[BIN_SIZE];
  const int b = blockIdx.x;
  const int t = threadIdx.x;
  const int s0 = binStart[b], s1 = binStart[b + 1];
  for (int k = t; k < BIN_SIZE * 16; k += 256) acc[k] = 0.f;
  for (int k = t; k < BIN_SIZE; k += 256) cnt[k] = 0;
  __syncthreads();
  const int o = t & 15, slot = t >> 4;
  for (int i = s0 + slot; i < s1; i += 16) {
    unsigned code = binned[i];
    int src = code >> BIN_SHIFT;
    int local = code & (BIN_SIZE - 1);
    atomicAdd(&acc[local * 16 + o], g_m[(size_t)src * 16 + o]);
    if (o == 0) atomicAdd(&cnt[local], 1);
  }
  __syncthreads();
  const int nodebase = b << BIN_SHIFT;
  for (int k = t; k < BIN_SIZE * 16; k += 256) {
    int local = k >> 4, oo = k & 15;
    int node = nodebase + local;
    float mean = acc[k] / fmaxf((float)cnt[local], 1.f);
    if (node < NU)
      pay_u[(size_t)node * 16 + oo] = ALPHA * g_u[(size_t)node * 16 + oo] + 0.5f * mean;
    else if (node < NU + ND)
      pay_d[(size_t)(node - NU) * 16 + oo] = ALPHA * g_d[(size_t)(node - NU) * 16 + oo] + 0.5f * mean;
  }
}

// ---------------- stage B accumulate: out = b + a^2*g_m + mean_r(pay_u) + mean_d(pay_d)
// Buckets interleaved: 2m = rates-acc of movie m, 2m+1 = dir-acc. One block owns
// BIN_SIZE/2 = 128 movies -> single writer per output row, no atomics.
__global__ __launch_bounds__(256) void accum_out_kernel(
    const unsigned* __restrict__ binned, const int* __restrict__ binStart,
    const float* __restrict__ pay_u, const float* __restrict__ pay_d,
    const float* __restrict__ g_m, const float* __restrict__ bo,
    float* __restrict__ out, int NM)
{
  __shared__ float acc[BIN_SIZE * 16];
  __shared__ int cnt[BIN_SIZE];
  const int b = blockIdx.x;
  const int t = threadIdx.x;
  const int s0 = binStart[b], s1 = binStart[b + 1];
  for (int k = t; k < BIN_SIZE * 16; k += 256) acc[k] = 0.f;
  for (int k = t; k < BIN_SIZE; k += 256) cnt[k] = 0;
  __syncthreads();
  const int o = t & 15, slot = t >> 4;
  for (int i = s0 + slot; i < s1; i += 16) {
    unsigned code = binned[i];
    int src = code >> BIN_SHIFT;
    int local = code & (BIN_SIZE - 1);
    const float* __restrict__ sa = (local & 1) ? pay_d : pay_u;
    atomicAdd(&acc[local * 16 + o], sa[(size_t)src * 16 + o]);
    if (o == 0) atomicAdd(&cnt[local], 1);
  }
  __syncthreads();
  const int mbase = b << (BIN_SHIFT - 1);
  for (int k = t; k < (BIN_SIZE / 2) * 16; k += 256) {
    int mi = k >> 4, oo = k & 15;
    int m = mbase + mi;
    if (m < NM) {
      float mr = acc[(mi * 2) * 16 + oo]     / fmaxf((float)cnt[mi * 2], 1.f);
      float md = acc[(mi * 2 + 1) * 16 + oo] / fmaxf((float)cnt[mi * 2 + 1], 1.f);
      out[(size_t)m * 16 + oo] = bo[oo] + ALPHA * ALPHA * g_m[(size_t)m * 16 + oo] + mr + md;
    }
  }
}

extern "C" void kernel_launch(void* const* d_in, const int* in_sizes, int n_in,
                              void* d_out, int out_size, void* d_ws, size_t ws_size,
                              hipStream_t stream)
{
  const float* x_user  = (const float*)d_in[0];
  const float* x_movie = (const float*)d_in[1];
  const float* x_dir   = (const float*)d_in[2];
  const int* rates_src = (const int*)d_in[3];
  const int* rates_dst = (const int*)d_in[4];
  const int* rby_src   = (const int*)d_in[5];
  const int* rby_dst   = (const int*)d_in[6];
  const int* dir_src   = (const int*)d_in[7];
  const int* dir_dst   = (const int*)d_in[8];
  const int* dby_src   = (const int*)d_in[9];
  const int* dby_dst   = (const int*)d_in[10];
  const float* W_user  = (const float*)d_in[11];
  const float* b_user  = (const float*)d_in[12];
  const float* W_movie = (const float*)d_in[13];
  const float* b_movie = (const float*)d_in[14];
  const float* W_dir   = (const float*)d_in[15];
  const float* b_dir   = (const float*)d_in[16];
  const float* W_out   = (const float*)d_in[17];
  const float* b_out   = (const float*)d_in[18];

  const int NU = in_sizes[0] / 128, NM = in_sizes[1] / 128, ND = in_sizes[2] / 128;
  const int Er = in_sizes[3], Erby = in_sizes[5], Edir = in_sizes[7], Edby = in_sizes[9];

  const int EA = Erby + Edby;                 // stage A: movies -> users/directors
  const int EB = Er + Edir;                   // stage B: users/directors -> movies
  const int nbinsA = (NU + ND + BIN_SIZE - 1) >> BIN_SHIFT;   // <= 1024
  const int nbinsB = (2 * NM + BIN_SIZE - 1) >> BIN_SHIFT;    // <= 1024

  // ---- workspace layout
  char* w = (char*)d_ws;
  size_t off = 0;
  auto take = [&](size_t bytes) { char* p = w + off; off += (bytes + 255) & ~(size_t)255; return p; };
  float* g_u   = (float*)take((size_t)NU * 16 * 4);
  float* g_m   = (float*)take((size_t)NM * 16 * 4);
  float* g_d   = (float*)take((size_t)ND * 16 * 4);
  float* pay_u = (float*)take((size_t)NU * 16 * 4);
  float* pay_d = (float*)take((size_t)ND * 16 * 4);
  size_t hist_begin = off;
  int* binHistA   = (int*)take(1024 * 4);     // zeroed
  int* binHistB   = (int*)take(1024 * 4);     // zeroed (contiguous with A)
  size_t hist_bytes = off - hist_begin;
  int* binStartA  = (int*)take(1025 * 4);
  int* binStartB  = (int*)take(1025 * 4);
  int* binCursorA = (int*)take(1024 * 4);
  int* binCursorB = (int*)take(1024 * 4);
  unsigned* binnedA = (unsigned*)take((size_t)EA * 4);
  unsigned* binnedB = (unsigned*)take((size_t)EB * 4);
  if (off > ws_size) return;

  // 1. zero bin histograms
  hipMemsetAsync(w + hist_begin, 0, hist_bytes, stream);

  // 2. coarse histograms  (A: rby dst=user, dby dst=NU+dir ; B: rates->2m, dir->2m+1)
  bin_hist_kernel<<<(EA + 255) / 256, 256, 0, stream>>>(
      rby_dst, Erby, dby_dst, Edby, 1, 0, 1, NU, nbinsA, binHistA);
  bin_hist_kernel<<<(EB + 255) / 256, 256, 0, stream>>>(
      rates_dst, Er, dir_dst, Edir, 2, 0, 2, 1, nbinsB, binHistB);

  // 3. scans
  bin_scan_kernel<<<1, 1024, 0, stream>>>(binHistA, binStartA, binCursorA, nbinsA);
  bin_scan_kernel<<<1, 1024, 0, stream>>>(binHistB, binStartB, binCursorB, nbinsB);

  // 4. binned fills
  bin_fill_kernel<<<(EA + 4095) / 4096, 256, 0, stream>>>(
      rby_src, rby_dst, Erby, dby_src, dby_dst, Edby, 1, 0, 1, NU,
      nbinsA, binCursorA, binnedA);
  bin_fill_kernel<<<(EB + 4095) / 4096, 256, 0, stream>>>(
      rates_src, rates_dst, Er, dir_src, dir_dst, Edir, 2, 0, 2, 1,
      nbinsB, binCursorB, binnedB);

  // 5. fused MFMA linear+relu+projection
  auto grid_for = [](int n) { int c = (n + 127) >> 7; return c < 512 ? c : 512; };
  fused_mfma_kernel<<<grid_for(NU), 256, 0, stream>>>(x_user,  W_user,  b_user,  W_out, g_u, NU);
  fused_mfma_kernel<<<grid_for(NM), 256, 0, stream>>>(x_movie, W_movie, b_movie, W_out, g_m, NM);
  fused_mfma_kernel<<<grid_for(ND), 256, 0, stream>>>(x_dir,   W_dir,   b_dir,   W_out, g_d, ND);

  // 6. stage A accumulate -> pay_u, pay_d
  accum_pay_kernel<<<nbinsA, 256, 0, stream>>>(
      binnedA, binStartA, g_m, g_u, g_d, NU, ND, pay_u, pay_d);

  // 7. stage B accumulate -> out
  accum_out_kernel<<<nbinsB, 256, 0, stream>>>(
      binnedB, binStartB, pay_u, pay_d, g_m, b_out, (float*)d_out, NM);
}

// Round 7
// 235.003 us; speedup vs baseline: 1.6807x; 1.6807x over previous
//
#include <hip/hip_runtime.h>

#define ALPHA 0.01f
#define BIN_SHIFT 10
#define SBIN 1024            // buckets per bin; nbins per stage <= 256

typedef __attribute__((ext_vector_type(8))) short short8v;   // 8 x bf16 bits (4 VGPR)
typedef __attribute__((ext_vector_type(4))) float float4v;   // MFMA acc

// split fp32 -> bf16 hi + bf16 lo (truncation; residual capture => ~2^-24 total rel err)
__device__ __forceinline__ void bsplit(float x, unsigned short& hi, unsigned short& lo) {
  unsigned u = __float_as_uint(x);
  hi = (unsigned short)(u >> 16);
  float r = x - __uint_as_float(u & 0xFFFF0000u);
  lo = (unsigned short)(__float_as_uint(r) >> 16);
}

__device__ __forceinline__ void frag_from8(const float* v, short8v& hi, short8v& lo) {
#pragma unroll
  for (int e = 0; e < 8; ++e) {
    unsigned short h, l;
    bsplit(v[e], h, l);
    hi[e] = (short)h;
    lo[e] = (short)l;
  }
}

// ---------------- fused MFMA: G[N,16] = relu(X[N,128] @ W^T + b) @ Wo^T ---------------
__global__ __launch_bounds__(256, 2) void fused_mfma_kernel(
    const float* __restrict__ X, const float* __restrict__ W,
    const float* __restrict__ B, const float* __restrict__ Wo,
    float* __restrict__ G, int N)
{
  __shared__ char smem[65536 + 10368] __attribute__((aligned(16)));
  unsigned short* Whi = (unsigned short*)smem;
  unsigned short* Wlo = (unsigned short*)(smem + 32768);
  unsigned short* WoHi = (unsigned short*)(smem + 65536);
  unsigned short* WoLo = (unsigned short*)(smem + 65536 + 4096);

  const int t = threadIdx.x;
  const int wave = t >> 6;
  const int lane = t & 63;
  const int s = lane & 15;
  const int q = lane >> 4;
  float* hbuf = (float*)(smem + 65536 + wave * 2176);  // [32][17] f32, per-wave

#pragma unroll
  for (int i = 0; i < 32; ++i) {
    int p = i * 256 + t;
    int row = p >> 6, c2 = p & 63;
    float w0 = W[row * 128 + c2 * 2];
    float w1 = W[row * 128 + c2 * 2 + 1];
    unsigned short h0, l0, h1, l1;
    bsplit(w0, h0, l0); bsplit(w1, h1, l1);
    int u32idx = row * 64 + ((((c2 * 4) ^ ((row & 7) << 4))) >> 2);
    ((unsigned*)Whi)[u32idx] = (unsigned)h0 | ((unsigned)h1 << 16);
    ((unsigned*)Wlo)[u32idx] = (unsigned)l0 | ((unsigned)l1 << 16);
  }
#pragma unroll
  for (int i = 0; i < 4; ++i) {
    int p = i * 256 + t;
    int row = p >> 6, c2 = p & 63;
    float w0 = Wo[row * 128 + c2 * 2];
    float w1 = Wo[row * 128 + c2 * 2 + 1];
    unsigned short h0, l0, h1, l1;
    bsplit(w0, h0, l0); bsplit(w1, h1, l1);
    int u32idx = row * 64 + ((((c2 * 4) ^ ((row & 7) << 4))) >> 2);
    ((unsigned*)WoHi)[u32idx] = (unsigned)h0 | ((unsigned)h1 << 16);
    ((unsigned*)WoLo)[u32idx] = (unsigned)l0 | ((unsigned)l1 << 16);
  }
  __syncthreads();

  short8v woh[4], wol[4];
  const int woswz = (s & 7) << 4;
#pragma unroll
  for (int ks = 0; ks < 4; ++ks) {
    int off = s * 256 + ((ks * 64 + q * 16) ^ woswz);
    woh[ks] = *(const short8v*)((char*)WoHi + off);
    wol[ks] = *(const short8v*)((char*)WoLo + off);
  }
  float bv[8];
#pragma unroll
  for (int nt = 0; nt < 8; ++nt) bv[nt] = B[nt * 16 + s];
  __syncthreads();  // Wo staging area now reusable as hbuf

  const int nchunks = (N + 127) >> 7;
  const int bswz = (s & 7) << 4;

  for (int chunk = blockIdx.x; chunk < nchunks; chunk += gridDim.x) {
    const int rowbase = chunk * 128 + wave * 32;

    short8v ahi[2][4], alo[2][4];
#pragma unroll
    for (int mt = 0; mt < 2; ++mt) {
      int row = rowbase + mt * 16 + s;
      int crow = row < N ? row : (N - 1);
      const float* xr = X + (size_t)crow * 128;
#pragma unroll
      for (int ks = 0; ks < 4; ++ks) {
        float4 f0 = *(const float4*)(xr + ks * 32 + q * 8);
        float4 f1 = *(const float4*)(xr + ks * 32 + q * 8 + 4);
        float v[8] = {f0.x, f0.y, f0.z, f0.w, f1.x, f1.y, f1.z, f1.w};
        frag_from8(v, ahi[mt][ks], alo[mt][ks]);
      }
    }

    float4v acc[2][8];
#pragma unroll
    for (int mt = 0; mt < 2; ++mt)
#pragma unroll
      for (int nt = 0; nt < 8; ++nt) acc[mt][nt] = (float4v){0.f, 0.f, 0.f, 0.f};

#pragma unroll
    for (int ks = 0; ks < 4; ++ks) {
      short8v bh[8];
#pragma unroll
      for (int nt = 0; nt < 8; ++nt) {
        int c = nt * 16 + s;
        int off = c * 256 + ((ks * 64 + q * 16) ^ bswz);
        bh[nt] = *(const short8v*)((char*)Whi + off);
      }
#pragma unroll
      for (int nt = 0; nt < 8; ++nt) {
#pragma unroll
        for (int mt = 0; mt < 2; ++mt) {
          acc[mt][nt] = __builtin_amdgcn_mfma_f32_16x16x32_bf16(ahi[mt][ks], bh[nt], acc[mt][nt], 0, 0, 0);
          acc[mt][nt] = __builtin_amdgcn_mfma_f32_16x16x32_bf16(alo[mt][ks], bh[nt], acc[mt][nt], 0, 0, 0);
        }
      }
#pragma unroll
      for (int nt = 0; nt < 8; ++nt) {
        int c = nt * 16 + s;
        int off = c * 256 + ((ks * 64 + q * 16) ^ bswz);
        short8v bl = *(const short8v*)((char*)Wlo + off);
#pragma unroll
        for (int mt = 0; mt < 2; ++mt)
          acc[mt][nt] = __builtin_amdgcn_mfma_f32_16x16x32_bf16(ahi[mt][ks], bl, acc[mt][nt], 0, 0, 0);
      }
    }

#pragma unroll
    for (int mt = 0; mt < 2; ++mt) {
      float4v gacc = (float4v){0.f, 0.f, 0.f, 0.f};
#pragma unroll
      for (int ks = 0; ks < 4; ++ks) {
#pragma unroll
        for (int j = 0; j < 2; ++j) {
          int nt = 2 * ks + j;
          int cl = j * 16 + s;
#pragma unroll
          for (int e = 0; e < 4; ++e)
            hbuf[cl * 17 + q * 4 + e] = fmaxf(acc[mt][nt][e] + bv[nt], 0.f);
        }
        float hv[8];
#pragma unroll
        for (int e = 0; e < 8; ++e) hv[e] = hbuf[(q * 8 + e) * 17 + s];
        short8v hh, hl;
        frag_from8(hv, hh, hl);
        gacc = __builtin_amdgcn_mfma_f32_16x16x32_bf16(hh, woh[ks], gacc, 0, 0, 0);
        gacc = __builtin_amdgcn_mfma_f32_16x16x32_bf16(hl, woh[ks], gacc, 0, 0, 0);
        gacc = __builtin_amdgcn_mfma_f32_16x16x32_bf16(hh, wol[ks], gacc, 0, 0, 0);
      }
      int grow = rowbase + mt * 16 + 4 * q;
#pragma unroll
      for (int e = 0; e < 4; ++e)
        if (grow + e < N) G[(size_t)(grow + e) * 16 + s] = gacc[e];
    }
  }
}

// ---------------- coarse bin histogram over two edge lists ---------------------------
// bucket = dst*mul + add (per list); bin = bucket >> BIN_SHIFT. nbins <= 256.
__global__ __launch_bounds__(256) void bin_hist_kernel(
    const int* __restrict__ dA, int EA, const int* __restrict__ dB, int EB,
    int mulA, int addA, int mulB, int addB, int nbins, int* __restrict__ binHist)
{
  __shared__ int h[256];
  for (int k = threadIdx.x; k < nbins; k += 256) h[k] = 0;
  __syncthreads();
  const int E = EA + EB;
  for (int i = blockIdx.x * 256 + threadIdx.x; i < E; i += gridDim.x * 256) {
    int bucket = (i < EA) ? dA[i] * mulA + addA : dB[i - EA] * mulB + addB;
    atomicAdd(&h[bucket >> BIN_SHIFT], 1);
  }
  __syncthreads();
  for (int k = threadIdx.x; k < nbins; k += 256)
    if (h[k]) atomicAdd(&binHist[k], h[k]);
}

// ---------------- exclusive scan over <=256 bins (single block) ----------------------
__global__ __launch_bounds__(256) void bin_scan_kernel(
    const int* __restrict__ hist, int* __restrict__ start, int* __restrict__ cursor, int n)
{
  __shared__ int tmp[256];
  int t = threadIdx.x;
  int v = (t < n) ? hist[t] : 0;
  tmp[t] = v;
  __syncthreads();
  for (int d = 1; d < 256; d <<= 1) {
    int add = (t >= d) ? tmp[t - d] : 0;
    __syncthreads();
    tmp[t] += add;
    __syncthreads();
  }
  int excl = tmp[t] - v;
  if (t < n) { start[t] = excl; cursor[t] = excl; }
  if (t == 255) start[n] = tmp[255];
}

// ---------------- binned fill: write packed codes bin-contiguously -------------------
// code = (src << BIN_SHIFT) | (bucket & (SBIN-1)). Per 4096-edge block: LDS hist, one
// global atomic per (block,bin) to reserve, clustered writes (~19 codes/bin ~ 76B).
__global__ __launch_bounds__(256) void bin_fill_kernel(
    const int* __restrict__ sA, const int* __restrict__ dA, int EA,
    const int* __restrict__ sB, const int* __restrict__ dB, int EB,
    int mulA, int addA, int mulB, int addB, int nbins,
    int* __restrict__ binCursor, unsigned* __restrict__ binned)
{
  __shared__ int h[256];
  __shared__ int base[256];
  const int E = EA + EB;
  const int c0 = blockIdx.x * 4096;
  const int c1 = (c0 + 4096 < E) ? c0 + 4096 : E;
  for (int k = threadIdx.x; k < nbins; k += 256) h[k] = 0;
  __syncthreads();
  for (int i = c0 + threadIdx.x; i < c1; i += 256) {
    int bucket = (i < EA) ? dA[i] * mulA + addA : dB[i - EA] * mulB + addB;
    atomicAdd(&h[bucket >> BIN_SHIFT], 1);
  }
  __syncthreads();
  for (int k = threadIdx.x; k < nbins; k += 256) {
    int c = h[k];
    base[k] = c ? atomicAdd(&binCursor[k], c) : 0;
    h[k] = 0;
  }
  __syncthreads();
  for (int i = c0 + threadIdx.x; i < c1; i += 256) {
    int s, bucket;
    if (i < EA) { s = sA[i]; bucket = dA[i] * mulA + addA; }
    else { int j = i - EA; s = sB[j]; bucket = dB[j] * mulB + addB; }
    int bin = bucket >> BIN_SHIFT;
    int r = atomicAdd(&h[bin], 1);
    binned[base[bin] + r] = ((unsigned)s << BIN_SHIFT) | (unsigned)(bucket & (SBIN - 1));
  }
}

// ---------------- bin scatter: exact CSR slots within each bin's window --------------
// One block per bin. Reads the bin's contiguous codes, LDS hist[1024] + scan -> global
// per-bucket offsets (replaces the old global hist+scan), then LDS-cursor re-rank and
// write ssrc into [binStart[b], binStart[b+1]) -- all writes inside one ~13KB window.
__global__ __launch_bounds__(256) void bin_scatter_kernel(
    const unsigned* __restrict__ binned, const int* __restrict__ binStart,
    int nbuckets, int* __restrict__ bOffs, int* __restrict__ bCnt,
    int* __restrict__ ssrc)
{
  __shared__ int cnt[SBIN];
  __shared__ int pref[SBIN];
  __shared__ int wsum[256];
  const int b = blockIdx.x, t = threadIdx.x;
  const int s0 = binStart[b], s1 = binStart[b + 1];
#pragma unroll
  for (int k = t; k < SBIN; k += 256) cnt[k] = 0;
  __syncthreads();
  for (int i = s0 + t; i < s1; i += 256)
    atomicAdd(&cnt[binned[i] & (SBIN - 1)], 1);
  __syncthreads();
  int c0 = cnt[4 * t], c1 = cnt[4 * t + 1], c2 = cnt[4 * t + 2], c3 = cnt[4 * t + 3];
  int s = c0 + c1 + c2 + c3;
  wsum[t] = s;
  __syncthreads();
  for (int d = 1; d < 256; d <<= 1) {
    int add = (t >= d) ? wsum[t - d] : 0;
    __syncthreads();
    wsum[t] += add;
    __syncthreads();
  }
  int base = wsum[t] - s;
  pref[4 * t]     = base;
  pref[4 * t + 1] = base + c0;
  pref[4 * t + 2] = base + c0 + c1;
  pref[4 * t + 3] = base + c0 + c1 + c2;
  __syncthreads();
  const int gb = b << BIN_SHIFT;
#pragma unroll
  for (int k = t; k < SBIN; k += 256) {
    int bucket = gb + k;
    if (bucket < nbuckets) { bOffs[bucket] = s0 + pref[k]; bCnt[bucket] = cnt[k]; }
  }
  __syncthreads();
#pragma unroll
  for (int k = t; k < SBIN; k += 256) cnt[k] = pref[k];
  __syncthreads();
  for (int i = s0 + t; i < s1; i += 256) {
    unsigned code = binned[i];
    int local = code & (SBIN - 1);
    int r = atomicAdd(&cnt[local], 1);
    ssrc[s0 + r] = (int)(code >> BIN_SHIFT);
  }
}

// ---------------- pay[node] = ALPHA*g_self[node] + 0.5*mean_CSR(g_src) ----------------
__global__ __launch_bounds__(256) void gather_pay_kernel(
    const float* __restrict__ g_src, const float* __restrict__ g_self,
    const int* __restrict__ bOffs, const int* __restrict__ bCnt, int nb,
    const int* __restrict__ ssrc, float* __restrict__ pay, int n)
{
  int tid = blockIdx.x * 256 + threadIdx.x;
  int node = tid >> 4, o = tid & 15;
  if (node >= n) return;
  int start = bOffs[nb + node], cnt = bCnt[nb + node];
  float sum = 0.f;
  for (int j = 0; j < cnt; ++j) {
    int s = ssrc[start + j];
    sum += g_src[(size_t)s * 16 + o];
  }
  pay[(size_t)node * 16 + o] =
      ALPHA * g_self[(size_t)node * 16 + o] + 0.5f * sum / fmaxf((float)cnt, 1.f);
}

// ---------------- out[m] = b_out + a^2*g_m[m] + mean_rates(pay_u) + mean_dir(pay_d) ---
// stage-B buckets interleaved: 2m = rates, 2m+1 = dir.
__global__ __launch_bounds__(256) void final_kernel(
    const float* __restrict__ gm, const float* __restrict__ pay_u,
    const float* __restrict__ pay_d,
    const int* __restrict__ bOffs, const int* __restrict__ bCnt,
    const int* __restrict__ ssrc,
    const float* __restrict__ bo, float* __restrict__ out, int NM)
{
  int tid = blockIdx.x * 256 + threadIdx.x;
  int m = tid >> 4, o = tid & 15;
  if (m >= NM) return;
  int s0 = bOffs[2 * m], c0 = bCnt[2 * m];
  float sr = 0.f;
  for (int j = 0; j < c0; ++j) sr += pay_u[(size_t)ssrc[s0 + j] * 16 + o];
  int s1 = bOffs[2 * m + 1], c1 = bCnt[2 * m + 1];
  float sd = 0.f;
  for (int j = 0; j < c1; ++j) sd += pay_d[(size_t)ssrc[s1 + j] * 16 + o];
  out[(size_t)m * 16 + o] = bo[o] + ALPHA * ALPHA * gm[(size_t)m * 16 + o]
                          + sr / fmaxf((float)c0, 1.f) + sd / fmaxf((float)c1, 1.f);
}

extern "C" void kernel_launch(void* const* d_in, const int* in_sizes, int n_in,
                              void* d_out, int out_size, void* d_ws, size_t ws_size,
                              hipStream_t stream)
{
  const float* x_user  = (const float*)d_in[0];
  const float* x_movie = (const float*)d_in[1];
  const float* x_dir   = (const float*)d_in[2];
  const int* rates_src = (const int*)d_in[3];
  const int* rates_dst = (const int*)d_in[4];
  const int* rby_src   = (const int*)d_in[5];
  const int* rby_dst   = (const int*)d_in[6];
  const int* dir_src   = (const int*)d_in[7];
  const int* dir_dst   = (const int*)d_in[8];
  const int* dby_src   = (const int*)d_in[9];
  const int* dby_dst   = (const int*)d_in[10];
  const float* W_user  = (const float*)d_in[11];
  const float* b_user  = (const float*)d_in[12];
  const float* W_movie = (const float*)d_in[13];
  const float* b_movie = (const float*)d_in[14];
  const float* W_dir   = (const float*)d_in[15];
  const float* b_dir   = (const float*)d_in[16];
  const float* W_out   = (const float*)d_in[17];
  const float* b_out   = (const float*)d_in[18];

  const int NU = in_sizes[0] / 128, NM = in_sizes[1] / 128, ND = in_sizes[2] / 128;
  const int Er = in_sizes[3], Erby = in_sizes[5], Edir = in_sizes[7], Edby = in_sizes[9];

  const int EA = Erby + Edby;                 // stage A: movies -> users/directors
  const int EB = Er + Edir;                   // stage B: users/directors -> movies
  const int HA = NU + ND;                     // stage A buckets
  const int HB = 2 * NM;                      // stage B buckets (interleaved)
  const int nbinsA = (HA + SBIN - 1) >> BIN_SHIFT;   // <= 256
  const int nbinsB = (HB + SBIN - 1) >> BIN_SHIFT;

  // ---- workspace layout
  char* w = (char*)d_ws;
  size_t off = 0;
  auto take = [&](size_t bytes) { char* p = w + off; off += (bytes + 255) & ~(size_t)255; return p; };
  float* g_u   = (float*)take((size_t)NU * 16 * 4);
  float* g_m   = (float*)take((size_t)NM * 16 * 4);
  float* g_d   = (float*)take((size_t)ND * 16 * 4);
  float* pay_u = (float*)take((size_t)NU * 16 * 4);
  float* pay_d = (float*)take((size_t)ND * 16 * 4);
  size_t hist_begin = off;
  int* binHistA   = (int*)take(256 * 4);      // zeroed
  int* binHistB   = (int*)take(256 * 4);      // zeroed (contiguous with A)
  size_t hist_bytes = off - hist_begin;
  int* binStartA  = (int*)take(257 * 4);
  int* binStartB  = (int*)take(257 * 4);
  int* binCursorA = (int*)take(256 * 4);
  int* binCursorB = (int*)take(256 * 4);
  int* bOffsA     = (int*)take((size_t)HA * 4);
  int* bCntA      = (int*)take((size_t)HA * 4);
  int* bOffsB     = (int*)take((size_t)HB * 4);
  int* bCntB      = (int*)take((size_t)HB * 4);
  unsigned* binnedA = (unsigned*)take((size_t)EA * 4);
  unsigned* binnedB = (unsigned*)take((size_t)EB * 4);
  int* ssrcA      = (int*)take((size_t)EA * 4);
  int* ssrcB      = (int*)take((size_t)EB * 4);
  if (off > ws_size) return;

  // 1. zero bin histograms
  hipMemsetAsync(w + hist_begin, 0, hist_bytes, stream);

  // 2. coarse histograms (A: rby dst=user, dby dst=NU+dir ; B: rates->2m, dir->2m+1)
  bin_hist_kernel<<<512, 256, 0, stream>>>(
      rby_dst, Erby, dby_dst, Edby, 1, 0, 1, NU, nbinsA, binHistA);
  bin_hist_kernel<<<512, 256, 0, stream>>>(
      rates_dst, Er, dir_dst, Edir, 2, 0, 2, 1, nbinsB, binHistB);

  // 3. bin scans
  bin_scan_kernel<<<1, 256, 0, stream>>>(binHistA, binStartA, binCursorA, nbinsA);
  bin_scan_kernel<<<1, 256, 0, stream>>>(binHistB, binStartB, binCursorB, nbinsB);

  // 4. binned fills (clustered code writes)
  bin_fill_kernel<<<(EA + 4095) / 4096, 256, 0, stream>>>(
      rby_src, rby_dst, Erby, dby_src, dby_dst, Edby, 1, 0, 1, NU,
      nbinsA, binCursorA, binnedA);
  bin_fill_kernel<<<(EB + 4095) / 4096, 256, 0, stream>>>(
      rates_src, rates_dst, Er, dir_src, dir_dst, Edir, 2, 0, 2, 1,
      nbinsB, binCursorB, binnedB);

  // 5. bin scatter -> exact CSR (ssrc) + per-bucket offs/cnt
  bin_scatter_kernel<<<nbinsA, 256, 0, stream>>>(
      binnedA, binStartA, HA, bOffsA, bCntA, ssrcA);
  bin_scatter_kernel<<<nbinsB, 256, 0, stream>>>(
      binnedB, binStartB, HB, bOffsB, bCntB, ssrcB);

  // 6. fused MFMA linear+relu+projection
  auto grid_for = [](int n) { int c = (n + 127) >> 7; return c < 512 ? c : 512; };
  fused_mfma_kernel<<<grid_for(NU), 256, 0, stream>>>(x_user,  W_user,  b_user,  W_out, g_u, NU);
  fused_mfma_kernel<<<grid_for(NM), 256, 0, stream>>>(x_movie, W_movie, b_movie, W_out, g_m, NM);
  fused_mfma_kernel<<<grid_for(ND), 256, 0, stream>>>(x_dir,   W_dir,   b_dir,   W_out, g_d, ND);

  // 7. pay_u = a*g_u + 0.5*mean_rby(g_m);  pay_d = a*g_d + 0.5*mean_dby(g_m)
  gather_pay_kernel<<<(NU * 16 + 255) / 256, 256, 0, stream>>>(
      g_m, g_u, bOffsA, bCntA, 0, ssrcA, pay_u, NU);
  gather_pay_kernel<<<(ND * 16 + 255) / 256, 256, 0, stream>>>(
      g_m, g_d, bOffsA, bCntA, NU, ssrcA, pay_d, ND);

  // 8. out = b_out + a^2*g_m + mean_rates(pay_u) + mean_dir(pay_d)
  final_kernel<<<(NM * 16 + 255) / 256, 256, 0, stream>>>(
      g_m, pay_u, pay_d, bOffsB, bCntB, ssrcB, b_out, (float*)d_out, NM);
}

// Round 8
// 176.020 us; speedup vs baseline: 2.2438x; 1.3351x over previous
//
#include <hip/hip_runtime.h>

#define ALPHA 0.01f
#define BIN_SHIFT 10
#define SBIN 1024            // buckets per bin; <=256 bins per stage

typedef __attribute__((ext_vector_type(8))) short short8v;   // 8 x bf16 bits (4 VGPR)
typedef __attribute__((ext_vector_type(4))) float float4v;   // MFMA acc

// split fp32 -> bf16 hi + bf16 lo (truncation; residual capture => ~2^-24 total rel err)
__device__ __forceinline__ void bsplit(float x, unsigned short& hi, unsigned short& lo) {
  unsigned u = __float_as_uint(x);
  hi = (unsigned short)(u >> 16);
  float r = x - __uint_as_float(u & 0xFFFF0000u);
  lo = (unsigned short)(__float_as_uint(r) >> 16);
}

__device__ __forceinline__ void frag_from8(const float* v, short8v& hi, short8v& lo) {
#pragma unroll
  for (int e = 0; e < 8; ++e) {
    unsigned short h, l;
    bsplit(v[e], h, l);
    hi[e] = (short)h;
    lo[e] = (short)l;
  }
}

// ---------------- fused MFMA for ALL ntypes: G = relu(X @ W^T + b) @ Wo^T -------------
// Static block partition (bu user / bm movie / rest dir); each block stages its W once.
__global__ __launch_bounds__(256, 2) void fused_mfma3_kernel(
    const float* __restrict__ Xu, const float* __restrict__ Xm, const float* __restrict__ Xd,
    const float* __restrict__ Wu, const float* __restrict__ Wm, const float* __restrict__ Wd,
    const float* __restrict__ Bu, const float* __restrict__ Bm, const float* __restrict__ Bd,
    const float* __restrict__ Wo,
    float* __restrict__ Gu, float* __restrict__ Gm, float* __restrict__ Gd,
    int NU, int NM, int ND, int bu, int bm)
{
  __shared__ char smem[65536 + 10368] __attribute__((aligned(16)));
  unsigned short* Whi = (unsigned short*)smem;
  unsigned short* Wlo = (unsigned short*)(smem + 32768);
  unsigned short* WoHi = (unsigned short*)(smem + 65536);
  unsigned short* WoLo = (unsigned short*)(smem + 65536 + 4096);

  // ---- block -> ntype partition (wave-uniform)
  const float *X, *W, *B;
  float* G;
  int N, bid, nbk;
  if ((int)blockIdx.x < bu)            { X = Xu; W = Wu; B = Bu; G = Gu; N = NU; bid = blockIdx.x;            nbk = bu; }
  else if ((int)blockIdx.x < bu + bm)  { X = Xm; W = Wm; B = Bm; G = Gm; N = NM; bid = blockIdx.x - bu;       nbk = bm; }
  else                                 { X = Xd; W = Wd; B = Bd; G = Gd; N = ND; bid = blockIdx.x - bu - bm;  nbk = gridDim.x - bu - bm; }

  const int t = threadIdx.x;
  const int wave = t >> 6;
  const int lane = t & 63;
  const int s = lane & 15;
  const int q = lane >> 4;
  float* hbuf = (float*)(smem + 65536 + wave * 2176);  // [32][17] f32, per-wave

#pragma unroll
  for (int i = 0; i < 32; ++i) {
    int p = i * 256 + t;
    int row = p >> 6, c2 = p & 63;
    float w0 = W[row * 128 + c2 * 2];
    float w1 = W[row * 128 + c2 * 2 + 1];
    unsigned short h0, l0, h1, l1;
    bsplit(w0, h0, l0); bsplit(w1, h1, l1);
    int u32idx = row * 64 + ((((c2 * 4) ^ ((row & 7) << 4))) >> 2);
    ((unsigned*)Whi)[u32idx] = (unsigned)h0 | ((unsigned)h1 << 16);
    ((unsigned*)Wlo)[u32idx] = (unsigned)l0 | ((unsigned)l1 << 16);
  }
#pragma unroll
  for (int i = 0; i < 4; ++i) {
    int p = i * 256 + t;
    int row = p >> 6, c2 = p & 63;
    float w0 = Wo[row * 128 + c2 * 2];
    float w1 = Wo[row * 128 + c2 * 2 + 1];
    unsigned short h0, l0, h1, l1;
    bsplit(w0, h0, l0); bsplit(w1, h1, l1);
    int u32idx = row * 64 + ((((c2 * 4) ^ ((row & 7) << 4))) >> 2);
    ((unsigned*)WoHi)[u32idx] = (unsigned)h0 | ((unsigned)h1 << 16);
    ((unsigned*)WoLo)[u32idx] = (unsigned)l0 | ((unsigned)l1 << 16);
  }
  __syncthreads();

  short8v woh[4], wol[4];
  const int woswz = (s & 7) << 4;
#pragma unroll
  for (int ks = 0; ks < 4; ++ks) {
    int off = s * 256 + ((ks * 64 + q * 16) ^ woswz);
    woh[ks] = *(const short8v*)((char*)WoHi + off);
    wol[ks] = *(const short8v*)((char*)WoLo + off);
  }
  float bv[8];
#pragma unroll
  for (int nt = 0; nt < 8; ++nt) bv[nt] = B[nt * 16 + s];
  __syncthreads();  // Wo staging area now reusable as hbuf

  const int nchunks = (N + 127) >> 7;
  const int bswz = (s & 7) << 4;

  for (int chunk = bid; chunk < nchunks; chunk += nbk) {
    const int rowbase = chunk * 128 + wave * 32;

    short8v ahi[2][4], alo[2][4];
#pragma unroll
    for (int mt = 0; mt < 2; ++mt) {
      int row = rowbase + mt * 16 + s;
      int crow = row < N ? row : (N - 1);
      const float* xr = X + (size_t)crow * 128;
#pragma unroll
      for (int ks = 0; ks < 4; ++ks) {
        float4 f0 = *(const float4*)(xr + ks * 32 + q * 8);
        float4 f1 = *(const float4*)(xr + ks * 32 + q * 8 + 4);
        float v[8] = {f0.x, f0.y, f0.z, f0.w, f1.x, f1.y, f1.z, f1.w};
        frag_from8(v, ahi[mt][ks], alo[mt][ks]);
      }
    }

    float4v acc[2][8];
#pragma unroll
    for (int mt = 0; mt < 2; ++mt)
#pragma unroll
      for (int nt = 0; nt < 8; ++nt) acc[mt][nt] = (float4v){0.f, 0.f, 0.f, 0.f};

#pragma unroll
    for (int ks = 0; ks < 4; ++ks) {
      short8v bh[8];
#pragma unroll
      for (int nt = 0; nt < 8; ++nt) {
        int c = nt * 16 + s;
        int off = c * 256 + ((ks * 64 + q * 16) ^ bswz);
        bh[nt] = *(const short8v*)((char*)Whi + off);
      }
#pragma unroll
      for (int nt = 0; nt < 8; ++nt) {
#pragma unroll
        for (int mt = 0; mt < 2; ++mt) {
          acc[mt][nt] = __builtin_amdgcn_mfma_f32_16x16x32_bf16(ahi[mt][ks], bh[nt], acc[mt][nt], 0, 0, 0);
          acc[mt][nt] = __builtin_amdgcn_mfma_f32_16x16x32_bf16(alo[mt][ks], bh[nt], acc[mt][nt], 0, 0, 0);
        }
      }
#pragma unroll
      for (int nt = 0; nt < 8; ++nt) {
        int c = nt * 16 + s;
        int off = c * 256 + ((ks * 64 + q * 16) ^ bswz);
        short8v bl = *(const short8v*)((char*)Wlo + off);
#pragma unroll
        for (int mt = 0; mt < 2; ++mt)
          acc[mt][nt] = __builtin_amdgcn_mfma_f32_16x16x32_bf16(ahi[mt][ks], bl, acc[mt][nt], 0, 0, 0);
      }
    }

#pragma unroll
    for (int mt = 0; mt < 2; ++mt) {
      float4v gacc = (float4v){0.f, 0.f, 0.f, 0.f};
#pragma unroll
      for (int ks = 0; ks < 4; ++ks) {
#pragma unroll
        for (int j = 0; j < 2; ++j) {
          int nt = 2 * ks + j;
          int cl = j * 16 + s;
#pragma unroll
          for (int e = 0; e < 4; ++e)
            hbuf[cl * 17 + q * 4 + e] = fmaxf(acc[mt][nt][e] + bv[nt], 0.f);
        }
        float hv[8];
#pragma unroll
        for (int e = 0; e < 8; ++e) hv[e] = hbuf[(q * 8 + e) * 17 + s];
        short8v hh, hl;
        frag_from8(hv, hh, hl);
        gacc = __builtin_amdgcn_mfma_f32_16x16x32_bf16(hh, woh[ks], gacc, 0, 0, 0);
        gacc = __builtin_amdgcn_mfma_f32_16x16x32_bf16(hl, woh[ks], gacc, 0, 0, 0);
        gacc = __builtin_amdgcn_mfma_f32_16x16x32_bf16(hh, wol[ks], gacc, 0, 0, 0);
      }
      int grow = rowbase + mt * 16 + 4 * q;
#pragma unroll
      for (int e = 0; e < 4; ++e)
        if (grow + e < N) G[(size_t)(grow + e) * 16 + s] = gacc[e];
    }
  }
}

// edge space order: [rby (Erby), dby (Edby), rates (Er), dir (Edir)]
// stage A buckets: user=yd, NU+bd   (bins 0..nbinsA)
// stage B buckets: 2*rd, 2*dd+1    (bins 256..256+nbinsB)
__device__ __forceinline__ void edge_decode(
    int i, const int* ys, const int* yd, int Erby,
    const int* bs, const int* bd, int Edby,
    const int* rs, const int* rd, int Er,
    const int* ds, const int* dd,
    int NU, int& src, int& bucket, int& bin)
{
  if (i < Erby)            { src = ys[i]; bucket = yd[i];                 bin = bucket >> BIN_SHIFT; }
  else if (i < Erby + Edby){ int j = i - Erby; src = bs[j]; bucket = NU + bd[j]; bin = bucket >> BIN_SHIFT; }
  else if (i < Erby + Edby + Er) { int j = i - Erby - Edby; src = rs[j]; bucket = 2 * rd[j]; bin = 256 + (bucket >> BIN_SHIFT); }
  else                     { int j = i - Erby - Edby - Er; src = ds[j]; bucket = 2 * dd[j] + 1; bin = 256 + (bucket >> BIN_SHIFT); }
}

// ---------------- combined coarse histogram (both stages, 512 LDS bins) --------------
__global__ __launch_bounds__(256) void hist2_kernel(
    const int* __restrict__ ys, const int* __restrict__ yd, int Erby,
    const int* __restrict__ bs, const int* __restrict__ bd, int Edby,
    const int* __restrict__ rs, const int* __restrict__ rd, int Er,
    const int* __restrict__ ds, const int* __restrict__ dd, int Edir,
    int NU, int* __restrict__ binHist)
{
  __shared__ int h[512];
  h[threadIdx.x] = 0; h[threadIdx.x + 256] = 0;
  __syncthreads();
  const int E = Erby + Edby + Er + Edir;
  for (int i = blockIdx.x * 256 + threadIdx.x; i < E; i += gridDim.x * 256) {
    int src, bucket, bin;
    edge_decode(i, ys, yd, Erby, bs, bd, Edby, rs, rd, Er, ds, dd, NU, src, bucket, bin);
    atomicAdd(&h[bin], 1);
  }
  __syncthreads();
  int v0 = h[threadIdx.x], v1 = h[threadIdx.x + 256];
  if (v0) atomicAdd(&binHist[threadIdx.x], v0);
  if (v1) atomicAdd(&binHist[threadIdx.x + 256], v1);
}

// ---------------- scans for both stages in one block ---------------------------------
// binStartA[257] over binHist[0..255], binStartB[257] over binHist[256..511];
// cursor[512] initialized to the exclusive prefixes.
__global__ __launch_bounds__(256) void scan2s_kernel(
    const int* __restrict__ binHist, int* __restrict__ binStartA,
    int* __restrict__ binStartB, int* __restrict__ cursor)
{
  __shared__ int tmp[256];
  const int t = threadIdx.x;
#pragma unroll
  for (int stage = 0; stage < 2; ++stage) {
    int v = binHist[stage * 256 + t];
    tmp[t] = v;
    __syncthreads();
    for (int d = 1; d < 256; d <<= 1) {
      int add = (t >= d) ? tmp[t - d] : 0;
      __syncthreads();
      tmp[t] += add;
      __syncthreads();
    }
    int excl = tmp[t] - v;
    int* bs = stage ? binStartB : binStartA;
    bs[t] = excl;
    cursor[stage * 256 + t] = excl;
    if (t == 255) bs[256] = tmp[255];
    __syncthreads();
  }
}

// ---------------- combined binned fill (both stages) ---------------------------------
__global__ __launch_bounds__(256) void fill2_kernel(
    const int* __restrict__ ys, const int* __restrict__ yd, int Erby,
    const int* __restrict__ bs, const int* __restrict__ bd, int Edby,
    const int* __restrict__ rs, const int* __restrict__ rd, int Er,
    const int* __restrict__ ds, const int* __restrict__ dd, int Edir,
    int NU, int* __restrict__ cursor,
    unsigned* __restrict__ binnedA, unsigned* __restrict__ binnedB)
{
  __shared__ int h[512];
  __shared__ int base[512];
  const int E = Erby + Edby + Er + Edir;
  const int c0 = blockIdx.x * 4096;
  const int c1 = (c0 + 4096 < E) ? c0 + 4096 : E;
  h[threadIdx.x] = 0; h[threadIdx.x + 256] = 0;
  __syncthreads();
  for (int i = c0 + threadIdx.x; i < c1; i += 256) {
    int src, bucket, bin;
    edge_decode(i, ys, yd, Erby, bs, bd, Edby, rs, rd, Er, ds, dd, NU, src, bucket, bin);
    atomicAdd(&h[bin], 1);
  }
  __syncthreads();
#pragma unroll
  for (int k = threadIdx.x; k < 512; k += 256) {
    int c = h[k];
    base[k] = c ? atomicAdd(&cursor[k], c) : 0;
    h[k] = 0;
  }
  __syncthreads();
  for (int i = c0 + threadIdx.x; i < c1; i += 256) {
    int src, bucket, bin;
    edge_decode(i, ys, yd, Erby, bs, bd, Edby, rs, rd, Er, ds, dd, NU, src, bucket, bin);
    int r = atomicAdd(&h[bin], 1);
    unsigned code = ((unsigned)src << BIN_SHIFT) | (unsigned)(bucket & (SBIN - 1));
    if (bin < 256) binnedA[base[bin] + r] = code;
    else           binnedB[base[bin] + r] = code;
  }
}

// ---------------- combined bin scatter (grid = nbinsA + nbinsB) ----------------------
__global__ __launch_bounds__(256) void scatter2_kernel(
    const unsigned* __restrict__ binnedA, const int* __restrict__ binStartA, int nbinsA, int HA,
    const unsigned* __restrict__ binnedB, const int* __restrict__ binStartB, int HB,
    int* __restrict__ bOffsA, int* __restrict__ bCntA,
    int* __restrict__ bOffsB, int* __restrict__ bCntB,
    int* __restrict__ ssrcA, int* __restrict__ ssrcB)
{
  __shared__ int cnt[SBIN];
  __shared__ int pref[SBIN];
  __shared__ int wsum[256];
  const int t = threadIdx.x;
  const unsigned* binned; const int* binStart;
  int* bOffs; int* bCnt; int* ssrc;
  int b, nbuckets;
  if ((int)blockIdx.x < nbinsA) {
    b = blockIdx.x; binned = binnedA; binStart = binStartA;
    bOffs = bOffsA; bCnt = bCntA; ssrc = ssrcA; nbuckets = HA;
  } else {
    b = blockIdx.x - nbinsA; binned = binnedB; binStart = binStartB;
    bOffs = bOffsB; bCnt = bCntB; ssrc = ssrcB; nbuckets = HB;
  }
  const int s0 = binStart[b], s1 = binStart[b + 1];
#pragma unroll
  for (int k = t; k < SBIN; k += 256) cnt[k] = 0;
  __syncthreads();
  for (int i = s0 + t; i < s1; i += 256)
    atomicAdd(&cnt[binned[i] & (SBIN - 1)], 1);
  __syncthreads();
  int c0 = cnt[4 * t], c1 = cnt[4 * t + 1], c2 = cnt[4 * t + 2], c3 = cnt[4 * t + 3];
  int s = c0 + c1 + c2 + c3;
  wsum[t] = s;
  __syncthreads();
  for (int d = 1; d < 256; d <<= 1) {
    int add = (t >= d) ? wsum[t - d] : 0;
    __syncthreads();
    wsum[t] += add;
    __syncthreads();
  }
  int base = wsum[t] - s;
  pref[4 * t]     = base;
  pref[4 * t + 1] = base + c0;
  pref[4 * t + 2] = base + c0 + c1;
  pref[4 * t + 3] = base + c0 + c1 + c2;
  __syncthreads();
  const int gb = b << BIN_SHIFT;
#pragma unroll
  for (int k = t; k < SBIN; k += 256) {
    int bucket = gb + k;
    if (bucket < nbuckets) { bOffs[bucket] = s0 + pref[k]; bCnt[bucket] = cnt[k]; }
  }
  __syncthreads();
#pragma unroll
  for (int k = t; k < SBIN; k += 256) cnt[k] = pref[k];
  __syncthreads();
  for (int i = s0 + t; i < s1; i += 256) {
    unsigned code = binned[i];
    int local = code & (SBIN - 1);
    int r = atomicAdd(&cnt[local], 1);
    ssrc[s0 + r] = (int)(code >> BIN_SHIFT);
  }
}

// ---------------- fused pay gather for users + directors -----------------------------
// A-bucket space: [0,NU)=users, [NU,NU+ND)=directors.
__global__ __launch_bounds__(256) void gather_pay2_kernel(
    const float* __restrict__ g_m, const float* __restrict__ g_u,
    const float* __restrict__ g_d,
    const int* __restrict__ bOffsA, const int* __restrict__ bCntA,
    const int* __restrict__ ssrcA,
    float* __restrict__ pay_u, float* __restrict__ pay_d, int NU, int ND)
{
  int tid = blockIdx.x * 256 + threadIdx.x;
  int node = tid >> 4, o = tid & 15;
  if (node >= NU + ND) return;
  int start = bOffsA[node], cnt = bCntA[node];
  float sum = 0.f;
  for (int j = 0; j < cnt; ++j) {
    int s = ssrcA[start + j];
    sum += g_m[(size_t)s * 16 + o];
  }
  float mean = 0.5f * sum / fmaxf((float)cnt, 1.f);
  if (node < NU)
    pay_u[(size_t)node * 16 + o] = ALPHA * g_u[(size_t)node * 16 + o] + mean;
  else {
    int nn = node - NU;
    pay_d[(size_t)nn * 16 + o] = ALPHA * g_d[(size_t)nn * 16 + o] + mean;
  }
}

// ---------------- out[m] = b_out + a^2*g_m[m] + mean_rates(pay_u) + mean_dir(pay_d) ---
__global__ __launch_bounds__(256) void final_kernel(
    const float* __restrict__ gm, const float* __restrict__ pay_u,
    const float* __restrict__ pay_d,
    const int* __restrict__ bOffs, const int* __restrict__ bCnt,
    const int* __restrict__ ssrc,
    const float* __restrict__ bo, float* __restrict__ out, int NM)
{
  int tid = blockIdx.x * 256 + threadIdx.x;
  int m = tid >> 4, o = tid & 15;
  if (m >= NM) return;
  int s0 = bOffs[2 * m], c0 = bCnt[2 * m];
  float sr = 0.f;
  for (int j = 0; j < c0; ++j) sr += pay_u[(size_t)ssrc[s0 + j] * 16 + o];
  int s1 = bOffs[2 * m + 1], c1 = bCnt[2 * m + 1];
  float sd = 0.f;
  for (int j = 0; j < c1; ++j) sd += pay_d[(size_t)ssrc[s1 + j] * 16 + o];
  out[(size_t)m * 16 + o] = bo[o] + ALPHA * ALPHA * gm[(size_t)m * 16 + o]
                          + sr / fmaxf((float)c0, 1.f) + sd / fmaxf((float)c1, 1.f);
}

extern "C" void kernel_launch(void* const* d_in, const int* in_sizes, int n_in,
                              void* d_out, int out_size, void* d_ws, size_t ws_size,
                              hipStream_t stream)
{
  const float* x_user  = (const float*)d_in[0];
  const float* x_movie = (const float*)d_in[1];
  const float* x_dir   = (const float*)d_in[2];
  const int* rates_src = (const int*)d_in[3];
  const int* rates_dst = (const int*)d_in[4];
  const int* rby_src   = (const int*)d_in[5];
  const int* rby_dst   = (const int*)d_in[6];
  const int* dir_src   = (const int*)d_in[7];
  const int* dir_dst   = (const int*)d_in[8];
  const int* dby_src   = (const int*)d_in[9];
  const int* dby_dst   = (const int*)d_in[10];
  const float* W_user  = (const float*)d_in[11];
  const float* b_user  = (const float*)d_in[12];
  const float* W_movie = (const float*)d_in[13];
  const float* b_movie = (const float*)d_in[14];
  const float* W_dir   = (const float*)d_in[15];
  const float* b_dir   = (const float*)d_in[16];
  const float* W_out   = (const float*)d_in[17];
  const float* b_out   = (const float*)d_in[18];

  const int NU = in_sizes[0] / 128, NM = in_sizes[1] / 128, ND = in_sizes[2] / 128;
  const int Er = in_sizes[3], Erby = in_sizes[5], Edir = in_sizes[7], Edby = in_sizes[9];

  const int EA = Erby + Edby;                 // stage A edges (movies -> users/dirs)
  const int EB = Er + Edir;                   // stage B edges (users/dirs -> movies)
  const int E  = EA + EB;
  const int HA = NU + ND;
  const int HB = 2 * NM;
  const int nbinsA = (HA + SBIN - 1) >> BIN_SHIFT;   // <= 256
  const int nbinsB = (HB + SBIN - 1) >> BIN_SHIFT;   // <= 256

  // ---- workspace layout
  char* w = (char*)d_ws;
  size_t off = 0;
  auto take = [&](size_t bytes) { char* p = w + off; off += (bytes + 255) & ~(size_t)255; return p; };
  float* g_u   = (float*)take((size_t)NU * 16 * 4);
  float* g_m   = (float*)take((size_t)NM * 16 * 4);
  float* g_d   = (float*)take((size_t)ND * 16 * 4);
  float* pay_u = (float*)take((size_t)NU * 16 * 4);
  float* pay_d = (float*)take((size_t)ND * 16 * 4);
  int* binHist    = (int*)take(512 * 4);      // zeroed
  int* binStartA  = (int*)take(257 * 4);
  int* binStartB  = (int*)take(257 * 4);
  int* cursor     = (int*)take(512 * 4);
  int* bOffsA     = (int*)take((size_t)HA * 4);
  int* bCntA      = (int*)take((size_t)HA * 4);
  int* bOffsB     = (int*)take((size_t)HB * 4);
  int* bCntB      = (int*)take((size_t)HB * 4);
  unsigned* binnedA = (unsigned*)take((size_t)EA * 4);
  unsigned* binnedB = (unsigned*)take((size_t)EB * 4);
  int* ssrcA      = (int*)take((size_t)EA * 4);
  int* ssrcB      = (int*)take((size_t)EB * 4);
  if (off > ws_size) return;

  // 1. zero 512-bin histogram
  hipMemsetAsync(binHist, 0, 512 * 4, stream);

  // 2. combined histogram (both stages, one pass over all 4 lists)
  hist2_kernel<<<512, 256, 0, stream>>>(
      rby_src, rby_dst, Erby, dby_src, dby_dst, Edby,
      rates_src, rates_dst, Er, dir_src, dir_dst, Edir, NU, binHist);

  // 3. both scans in one block
  scan2s_kernel<<<1, 256, 0, stream>>>(binHist, binStartA, binStartB, cursor);

  // 4. combined binned fill (clustered code writes)
  fill2_kernel<<<(E + 4095) / 4096, 256, 0, stream>>>(
      rby_src, rby_dst, Erby, dby_src, dby_dst, Edby,
      rates_src, rates_dst, Er, dir_src, dir_dst, Edir, NU,
      cursor, binnedA, binnedB);

  // 5. combined bin scatter -> exact CSR + per-bucket offs/cnt
  scatter2_kernel<<<nbinsA + nbinsB, 256, 0, stream>>>(
      binnedA, binStartA, nbinsA, HA, binnedB, binStartB, HB,
      bOffsA, bCntA, bOffsB, bCntB, ssrcA, ssrcB);

  // 6. one MFMA launch for all three ntypes (proportional static partition of 512 blks)
  {
    long long cu = (NU + 127) >> 7, cm = (NM + 127) >> 7, cd = (ND + 127) >> 7;
    long long ct = cu + cm + cd;
    int bu = (int)((512 * cu + ct / 2) / ct);
    int bm = (int)((512 * cm + ct / 2) / ct);
    if (bu < 1) bu = 1;
    if (bm < 1) bm = 1;
    if (bu + bm > 510) { bu = 510 * bu / (bu + bm); bm = 510 - bu; }
    fused_mfma3_kernel<<<512, 256, 0, stream>>>(
        x_user, x_movie, x_dir, W_user, W_movie, W_dir,
        b_user, b_movie, b_dir, W_out, g_u, g_m, g_d,
        NU, NM, ND, bu, bm);
  }

  // 7. fused pay gather (users + directors)
  gather_pay2_kernel<<<((NU + ND) * 16 + 255) / 256, 256, 0, stream>>>(
      g_m, g_u, g_d, bOffsA, bCntA, ssrcA, pay_u, pay_d, NU, ND);

  // 8. out = b_out + a^2*g_m + mean_rates(pay_u) + mean_dir(pay_d)
  final_kernel<<<(NM * 16 + 255) / 256, 256, 0, stream>>>(
      g_m, pay_u, pay_d, bOffsB, bCntB, ssrcB, b_out, (float*)d_out, NM);
}